// Round 1
// baseline (1055.424 us; speedup 1.0000x reference)
//
#include <hip/hip_runtime.h>

typedef unsigned short u16;
typedef float f32x4 __attribute__((ext_vector_type(4)));
typedef short bf16x8 __attribute__((ext_vector_type(8)));
typedef u16 u16x4 __attribute__((ext_vector_type(4)));

// B=2, C=64, D=3, N=4096, K=16, E=128, H=256

static __device__ __forceinline__ u16 f2bf(float x) {
    union { float f; unsigned int u; } v; v.f = x;
    unsigned int u = v.u;
    unsigned int r = u + 0x7fffu + ((u >> 16) & 1u);   // RNE
    return (u16)(r >> 16);
}

// ---------------- mean over D ----------------
__global__ __launch_bounds__(256) void mean_kernel(const float* __restrict__ x,
                                                   float* __restrict__ pc) {
    int t = blockIdx.x * 256 + threadIdx.x;            // over B*C*N = 524288
    int n = t & 4095;
    int bc = t >> 12;
    const float* xp = x + ((size_t)bc * 3) * 4096 + n;
    pc[t] = (xp[0] + xp[4096] + xp[8192]) / 3.0f;
}

// ---------------- per-point squared norm ----------------
__global__ __launch_bounds__(256) void sq_kernel(const float* __restrict__ pc,
                                                 float* __restrict__ sq) {
    int t = blockIdx.x * 256 + threadIdx.x;            // over B*N = 8192
    int b = t >> 12, n = t & 4095;
    float s = 0.f;
    #pragma unroll
    for (int c = 0; c < 64; ++c) {
        float v = pc[((size_t)(b * 64 + c)) * 4096 + n];
        s += v * v;
    }
    sq[t] = s;
}

#define CONSIDER(dist, idxv) do { \
    if ((dist) < bd[15]) { \
        float _vd = (dist); int _vi = (idxv); \
        _Pragma("unroll") \
        for (int _s = 0; _s < 16; ++_s) { \
            if (_vd < bd[_s]) { \
                float _td = bd[_s]; bd[_s] = _vd; _vd = _td; \
                int _ti = bi[_s]; bi[_s] = _vi; _vi = _ti; } \
        } \
    } } while (0)

// ---------------- KNN phase 1: per-chunk top-16 ----------------
// grid = B(2) * QB(16) * CH(8) = 256 blocks, 256 threads (1 query/thread)
__global__ __launch_bounds__(256) void knn_part_kernel(const float* __restrict__ pc,
                                                       const float* __restrict__ sq,
                                                       float* __restrict__ pd,
                                                       int* __restrict__ pi) {
    __shared__ float ptile[64][128];
    __shared__ float sqt[128];
    int tid = threadIdx.x;
    int bid = blockIdx.x;
    int ch = bid & 7, qb = (bid >> 3) & 15, b = bid >> 7;
    int n = qb * 256 + tid;

    float qv[64];
    #pragma unroll
    for (int c = 0; c < 64; ++c) qv[c] = pc[((size_t)(b * 64 + c)) * 4096 + n];
    float sqn = sq[b * 4096 + n];

    float bd[16]; int bi[16];
    #pragma unroll
    for (int s = 0; s < 16; ++s) { bd[s] = 3.4e38f; bi[s] = -1; }

    for (int mt = 0; mt < 4; ++mt) {
        int m0 = ch * 512 + mt * 128;
        __syncthreads();
        #pragma unroll
        for (int r = 0; r < 32; ++r) {
            int lin = r * 256 + tid;
            int c = lin >> 7, mm = lin & 127;
            ptile[c][mm] = pc[((size_t)(b * 64 + c)) * 4096 + m0 + mm];
        }
        if (tid < 128) sqt[tid] = sq[b * 4096 + m0 + tid];
        __syncthreads();

        for (int mb = 0; mb < 128; mb += 4) {
            float d0 = 0.f, d1 = 0.f, d2 = 0.f, d3 = 0.f;
            #pragma unroll
            for (int c = 0; c < 64; ++c) {
                float4 pv = *(const float4*)&ptile[c][mb];
                float qc = qv[c];
                d0 = fmaf(qc, pv.x, d0);
                d1 = fmaf(qc, pv.y, d1);
                d2 = fmaf(qc, pv.z, d2);
                d3 = fmaf(qc, pv.w, d3);
            }
            int m = m0 + mb;
            float e0 = (sqn - 2.f * d0) + sqt[mb + 0]; if (m + 0 == n) e0 = 3.4e38f;
            float e1 = (sqn - 2.f * d1) + sqt[mb + 1]; if (m + 1 == n) e1 = 3.4e38f;
            float e2 = (sqn - 2.f * d2) + sqt[mb + 2]; if (m + 2 == n) e2 = 3.4e38f;
            float e3 = (sqn - 2.f * d3) + sqt[mb + 3]; if (m + 3 == n) e3 = 3.4e38f;
            CONSIDER(e0, m + 0);
            CONSIDER(e1, m + 1);
            CONSIDER(e2, m + 2);
            CONSIDER(e3, m + 3);
        }
    }
    size_t base = (((size_t)(b * 4096 + n)) * 8 + ch) * 16;
    #pragma unroll
    for (int s = 0; s < 16; ++s) { pd[base + s] = bd[s]; pi[base + s] = bi[s]; }
}

// ---------------- KNN phase 2: merge chunks ----------------
__global__ __launch_bounds__(256) void knn_merge_kernel(const float* __restrict__ pd,
                                                        const int* __restrict__ pi,
                                                        int* __restrict__ idxw) {
    int t = blockIdx.x * 256 + threadIdx.x;            // over B*N = 8192
    float bd[16]; int bi[16];
    #pragma unroll
    for (int s = 0; s < 16; ++s) { bd[s] = 3.4e38f; bi[s] = -1; }
    size_t base = (size_t)t * 128;
    for (int s = 0; s < 128; ++s) {
        float dv = pd[base + s];
        int iv = pi[base + s];
        CONSIDER(dv, iv);
    }
    #pragma unroll
    for (int k = 0; k < 16; ++k) idxw[t * 16 + k] = bi[k];
}

// ---------------- weight prep: bf16 W2/W3, split+transpose W1 ----------------
__global__ __launch_bounds__(256) void prep_kernel(const float* __restrict__ W1,
                                                   const float* __restrict__ W2,
                                                   const float* __restrict__ W3,
                                                   u16* __restrict__ W2bf,
                                                   u16* __restrict__ W3bf,
                                                   float* __restrict__ W1dT,
                                                   float* __restrict__ W1bT) {
    int t = blockIdx.x * 256 + threadIdx.x;            // 65536
    W2bf[t] = f2bf(W2[t]);
    if (t < 16384) {
        W3bf[t] = f2bf(W3[t]);
        int c = t >> 8, h = t & 255;
        float wa = W1[h * 128 + c];
        float wb = W1[h * 128 + 64 + c];
        W1dT[t] = wa - wb;                             // [c][h]
        W1bT[t] = wb;                                  // [c][h]
    }
}

// ---------------- Qn[b][m][h] = W1b @ mean_pc ----------------
__global__ __launch_bounds__(256) void q_kernel(const float* __restrict__ pc,
                                                const float* __restrict__ W1bT,
                                                float* __restrict__ Qn) {
    int h = threadIdx.x;
    int bid = blockIdx.x;                              // 2048
    int b = bid >> 10, m0 = (bid & 1023) * 4;
    float a0 = 0.f, a1 = 0.f, a2 = 0.f, a3 = 0.f;
    for (int c = 0; c < 64; ++c) {
        float w = W1bT[c * 256 + h];
        const float* pr = pc + ((size_t)(b * 64 + c)) * 4096 + m0;
        a0 = fmaf(w, pr[0], a0);
        a1 = fmaf(w, pr[1], a1);
        a2 = fmaf(w, pr[2], a2);
        a3 = fmaf(w, pr[3], a3);
    }
    size_t ob = ((size_t)(b * 4096 + m0)) * 256 + h;
    Qn[ob] = a0; Qn[ob + 256] = a1; Qn[ob + 512] = a2; Qn[ob + 768] = a3;
}

// ---------------- P[b][d][n][h] = (W1a-W1b) @ x + b1 ----------------
__global__ __launch_bounds__(256) void p_kernel(const float* __restrict__ x,
                                                const float* __restrict__ W1dT,
                                                const float* __restrict__ b1,
                                                float* __restrict__ P) {
    int h = threadIdx.x;
    int bid = blockIdx.x;                              // 6144
    int b = bid / 3072;
    int rem = bid % 3072;
    int d = rem >> 10;
    int n0 = (rem & 1023) * 4;
    float bias = b1[h];
    float a0 = bias, a1 = bias, a2 = bias, a3 = bias;
    for (int c = 0; c < 64; ++c) {
        float w = W1dT[c * 256 + h];
        const float* xr = x + ((size_t)((b * 64 + c) * 3 + d)) * 4096 + n0;
        a0 = fmaf(w, xr[0], a0);
        a1 = fmaf(w, xr[1], a1);
        a2 = fmaf(w, xr[2], a2);
        a3 = fmaf(w, xr[3], a3);
    }
    size_t ob = ((size_t)((b * 3 + d) * 4096 + n0)) * 256 + h;
    P[ob] = a0; P[ob + 256] = a1; P[ob + 512] = a2; P[ob + 768] = a3;
}

// ---------------- fused layer2+layer3+maxK+residual (bf16 MFMA) ----------------
// one block = 2 points (G=2): 96 columns (g,d,k), 256 threads = 4 waves
__global__ __launch_bounds__(256) void fused_mlp_kernel(const float* __restrict__ x,
                                                        const float* __restrict__ P,
                                                        const float* __restrict__ Qn,
                                                        const int* __restrict__ idxw,
                                                        const u16* __restrict__ W2bf,
                                                        const u16* __restrict__ W3bf,
                                                        const float* __restrict__ b2,
                                                        const float* __restrict__ b3,
                                                        float* __restrict__ out) {
    __shared__ u16 hL[96][264];                        // stride 264: 16B-aligned rows, 2-way banks
    __shared__ float b2s[256];
    __shared__ float b3s[64];
    __shared__ int idxs[32];

    int tid = threadIdx.x;
    int bid = blockIdx.x;                              // 4096
    int b = bid >> 11;
    int n0 = (bid & 2047) * 2;

    b2s[tid] = b2[tid];
    if (tid < 64) b3s[tid] = b3[tid];
    if (tid < 32) {
        int g = tid >> 4, k = tid & 15;
        idxs[tid] = idxw[((size_t)(b * 4096 + n0 + g)) * 16 + k];
    }
    __syncthreads();

    // ---- build h1 = relu(P + Q) into LDS (bf16) ----
    int tsub = tid & 63, jgrp = tid >> 6;
    for (int it = 0; it < 24; ++it) {
        int j = it * 4 + jgrp;                         // 0..95
        int g = j / 48, jj = j % 48;
        int d = jj >> 4, k = jj & 15;
        int m = idxs[g * 16 + k];
        const float4* Pp = (const float4*)(P + ((size_t)((b * 3 + d) * 4096 + (n0 + g))) * 256) + tsub;
        const float4* Qp = (const float4*)(Qn + ((size_t)(b * 4096 + m)) * 256) + tsub;
        float4 pv = *Pp;
        float4 qv = *Qp;
        u16x4 hv;
        hv[0] = f2bf(fmaxf(pv.x + qv.x, 0.f));
        hv[1] = f2bf(fmaxf(pv.y + qv.y, 0.f));
        hv[2] = f2bf(fmaxf(pv.z + qv.z, 0.f));
        hv[3] = f2bf(fmaxf(pv.w + qv.w, 0.f));
        *(u16x4*)&hL[j][tsub * 4] = hv;
    }
    __syncthreads();

    int w = tid >> 6, lane = tid & 63;
    int cl = lane & 15, q = lane >> 4;

    // ---- layer 2: h2 = relu(W2 @ h1 + b2), 256 rows x 96 cols ----
    f32x4 acc[4][6];
    #pragma unroll
    for (int i = 0; i < 4; ++i)
        #pragma unroll
        for (int jt = 0; jt < 6; ++jt)
            acc[i][jt] = (f32x4){0.f, 0.f, 0.f, 0.f};

    const u16* Arow = W2bf + ((size_t)(w * 64 + cl)) * 256 + q * 8;
    for (int kt = 0; kt < 8; ++kt) {
        int k0 = kt * 32;
        bf16x8 a[4], bb[6];
        #pragma unroll
        for (int i = 0; i < 4; ++i)
            a[i] = *(const bf16x8*)(Arow + i * 16 * 256 + k0);
        #pragma unroll
        for (int jt = 0; jt < 6; ++jt)
            bb[jt] = *(const bf16x8*)(&hL[jt * 16 + cl][k0 + q * 8]);
        #pragma unroll
        for (int i = 0; i < 4; ++i)
            #pragma unroll
            for (int jt = 0; jt < 6; ++jt)
                acc[i][jt] = __builtin_amdgcn_mfma_f32_16x16x32_bf16(a[i], bb[jt], acc[i][jt], 0, 0, 0);
    }
    __syncthreads();   // everyone done reading h1

    // write h2 (bf16) into the same LDS buffer
    #pragma unroll
    for (int i = 0; i < 4; ++i) {
        int rowb = w * 64 + i * 16 + q * 4;
        #pragma unroll
        for (int jt = 0; jt < 6; ++jt) {
            f32x4 v = acc[i][jt];
            u16x4 hv;
            hv[0] = f2bf(fmaxf(v[0] + b2s[rowb + 0], 0.f));
            hv[1] = f2bf(fmaxf(v[1] + b2s[rowb + 1], 0.f));
            hv[2] = f2bf(fmaxf(v[2] + b2s[rowb + 2], 0.f));
            hv[3] = f2bf(fmaxf(v[3] + b2s[rowb + 3], 0.f));
            *(u16x4*)&hL[jt * 16 + cl][rowb] = hv;
        }
    }
    __syncthreads();

    // ---- layer 3: r = W3 @ h2 + b3, 64 rows x 96 cols; wave w -> rows w*16..w*16+15 ----
    f32x4 acc3[6];
    #pragma unroll
    for (int jt = 0; jt < 6; ++jt) acc3[jt] = (f32x4){0.f, 0.f, 0.f, 0.f};

    const u16* A3row = W3bf + ((size_t)(w * 16 + cl)) * 256 + q * 8;
    for (int kt = 0; kt < 8; ++kt) {
        int k0 = kt * 32;
        bf16x8 a3 = *(const bf16x8*)(A3row + k0);
        #pragma unroll
        for (int jt = 0; jt < 6; ++jt) {
            bf16x8 bb = *(const bf16x8*)(&hL[jt * 16 + cl][k0 + q * 8]);
            acc3[jt] = __builtin_amdgcn_mfma_f32_16x16x32_bf16(a3, bb, acc3[jt], 0, 0, 0);
        }
    }

    // ---- epilogue: +b3, max over k (16 cols of each tile), +x, store ----
    #pragma unroll
    for (int jt = 0; jt < 6; ++jt) {
        int g = jt / 3, d = jt % 3;
        int n = n0 + g;
        int rowb = w * 16 + q * 4;
        f32x4 v = acc3[jt];
        v[0] += b3s[rowb + 0];
        v[1] += b3s[rowb + 1];
        v[2] += b3s[rowb + 2];
        v[3] += b3s[rowb + 3];
        #pragma unroll
        for (int off = 1; off < 16; off <<= 1) {
            v[0] = fmaxf(v[0], __shfl_xor(v[0], off));
            v[1] = fmaxf(v[1], __shfl_xor(v[1], off));
            v[2] = fmaxf(v[2], __shfl_xor(v[2], off));
            v[3] = fmaxf(v[3], __shfl_xor(v[3], off));
        }
        if (cl == 0) {
            #pragma unroll
            for (int r = 0; r < 4; ++r) {
                size_t addr = ((size_t)((b * 64 + rowb + r) * 3 + d)) * 4096 + n;
                out[addr] = v[r] + x[addr];
            }
        }
    }
}

extern "C" void kernel_launch(void* const* d_in, const int* in_sizes, int n_in,
                              void* d_out, int out_size, void* d_ws, size_t ws_size,
                              hipStream_t stream) {
    (void)in_sizes; (void)n_in; (void)out_size; (void)ws_size;
    const float* x  = (const float*)d_in[0];
    const float* W1 = (const float*)d_in[1];
    const float* b1 = (const float*)d_in[2];
    const float* W2 = (const float*)d_in[3];
    const float* b2 = (const float*)d_in[4];
    const float* W3 = (const float*)d_in[5];
    const float* b3 = (const float*)d_in[6];
    float* out = (float*)d_out;

    char* ws = (char*)d_ws;
    float* pc   = (float*)(ws + 0);          // 2,097,152 B  (B,C,N)
    float* sq   = (float*)(ws + 2097152);    //    32,768 B  (B,N)
    int*   idxw = (int*)  (ws + 2129920);    //   524,288 B  (B,N,K)
    float* Qn   = (float*)(ws + 2654208);    // 8,388,608 B  (B,N,H)
    float* P    = (float*)(ws + 11042816);   // 25,165,824 B (B,D,N,H)
    u16*   W2bf = (u16*)  (ws + 36208640);   //   131,072 B
    u16*   W3bf = (u16*)  (ws + 36339712);   //    32,768 B
    float* W1dT = (float*)(ws + 36372480);   //    65,536 B
    float* W1bT = (float*)(ws + 36438016);   //    65,536 B
    // KNN partials alias the (not-yet-written) P region:
    float* pd   = (float*)(ws + 11042816);   // 4,194,304 B
    int*   pi   = (int*)  (ws + 15237120);   // 4,194,304 B

    mean_kernel<<<2048, 256, 0, stream>>>(x, pc);
    sq_kernel<<<32, 256, 0, stream>>>(pc, sq);
    knn_part_kernel<<<256, 256, 0, stream>>>(pc, sq, pd, pi);
    knn_merge_kernel<<<32, 256, 0, stream>>>(pd, pi, idxw);
    prep_kernel<<<256, 256, 0, stream>>>(W1, W2, W3, W2bf, W3bf, W1dT, W1bT);
    q_kernel<<<2048, 256, 0, stream>>>(pc, W1bT, Qn);
    p_kernel<<<6144, 256, 0, stream>>>(x, W1dT, b1, P);
    fused_mlp_kernel<<<4096, 256, 0, stream>>>(x, P, Qn, idxw, W2bf, W3bf, b2, b3, out);
}

// Round 2
// 407.911 us; speedup vs baseline: 2.5874x; 2.5874x over previous
//
#include <hip/hip_runtime.h>

typedef unsigned short u16;
typedef float f32x4 __attribute__((ext_vector_type(4)));
typedef short bf16x8 __attribute__((ext_vector_type(8)));
typedef u16 u16x4 __attribute__((ext_vector_type(4)));

// B=2, C=64, D=3, N=4096, K=16, E=128, H=256

static __device__ __forceinline__ u16 f2bf(float x) {
    union { float f; unsigned int u; } v; v.f = x;
    unsigned int u = v.u;
    unsigned int r = u + 0x7fffu + ((u >> 16) & 1u);   // RNE
    return (u16)(r >> 16);
}

// ---------------- mean over D ----------------
__global__ __launch_bounds__(256) void mean_kernel(const float* __restrict__ x,
                                                   float* __restrict__ pc) {
    int t = blockIdx.x * 256 + threadIdx.x;            // over B*C*N = 524288
    int n = t & 4095;
    int bc = t >> 12;
    const float* xp = x + ((size_t)bc * 3) * 4096 + n;
    pc[t] = (xp[0] + xp[4096] + xp[8192]) / 3.0f;
}

// ---------------- per-point squared norm ----------------
__global__ __launch_bounds__(256) void sq_kernel(const float* __restrict__ pc,
                                                 float* __restrict__ sq) {
    int t = blockIdx.x * 256 + threadIdx.x;            // over B*N = 8192
    int b = t >> 12, n = t & 4095;
    float s = 0.f;
    #pragma unroll
    for (int c = 0; c < 64; ++c) {
        float v = pc[((size_t)(b * 64 + c)) * 4096 + n];
        s += v * v;
    }
    sq[t] = s;
}

// Branch-free sorted insert: exact fp32 compare, 5 VALU/step, no divergence.
#define INSERT(dist, idxv) do { \
    float _v = (dist); int _vi = (idxv); \
    _Pragma("unroll") \
    for (int _s = 0; _s < 16; ++_s) { \
        bool _c = _v < bd[_s]; \
        float _nb = _c ? _v : bd[_s]; \
        float _nv = _c ? bd[_s] : _v; \
        int _nbi = _c ? _vi : bi[_s]; \
        int _nvi = _c ? bi[_s] : _vi; \
        bd[_s] = _nb; _v = _nv; bi[_s] = _nbi; _vi = _nvi; \
    } } while (0)

// ---------------- KNN phase 1: per-chunk top-16 ----------------
// grid = B(2) * QB(16) * CH(32) = 1024 blocks, 256 threads (1 query/thread),
// 128 candidates per chunk. launch_bounds(,3): target 3 blocks/CU (LDS 33 KB).
__global__ __launch_bounds__(256, 3) void knn_part_kernel(const float* __restrict__ pc,
                                                          const float* __restrict__ sq,
                                                          float* __restrict__ pd,
                                                          int* __restrict__ pi) {
    __shared__ float ptile[64][128];
    __shared__ float sqt[128];
    int tid = threadIdx.x;
    int bid = blockIdx.x;
    int ch = bid & 31, qb = (bid >> 5) & 15, b = bid >> 9;
    int n = qb * 256 + tid;
    int m0 = ch * 128;

    // stage candidate tile (64 c x 128 m) via float4, coalesced
    #pragma unroll
    for (int it = 0; it < 8; ++it) {
        int lin4 = it * 256 + tid;                     // 2048 float4s
        int c = lin4 >> 5, mm4 = (lin4 & 31) * 4;
        *(float4*)&ptile[c][mm4] =
            *(const float4*)&pc[((size_t)(b * 64 + c)) * 4096 + m0 + mm4];
    }
    if (tid < 128) sqt[tid] = sq[b * 4096 + m0 + tid];

    float qv[64];
    #pragma unroll
    for (int c = 0; c < 64; ++c) qv[c] = pc[((size_t)(b * 64 + c)) * 4096 + n];
    float sqn = sq[b * 4096 + n];

    float bd[16]; int bi[16];
    #pragma unroll
    for (int s = 0; s < 16; ++s) { bd[s] = 3.4e38f; bi[s] = -1; }
    __syncthreads();

    for (int mb = 0; mb < 128; mb += 4) {
        float d0 = 0.f, d1 = 0.f, d2 = 0.f, d3 = 0.f;
        #pragma unroll
        for (int c = 0; c < 64; ++c) {
            float4 pv = *(const float4*)&ptile[c][mb];
            float qc = qv[c];
            d0 = fmaf(qc, pv.x, d0);
            d1 = fmaf(qc, pv.y, d1);
            d2 = fmaf(qc, pv.z, d2);
            d3 = fmaf(qc, pv.w, d3);
        }
        int m = m0 + mb;
        float e0 = (sqn - 2.f * d0) + sqt[mb + 0]; if (m + 0 == n) e0 = 3.4e38f;
        float e1 = (sqn - 2.f * d1) + sqt[mb + 1]; if (m + 1 == n) e1 = 3.4e38f;
        float e2 = (sqn - 2.f * d2) + sqt[mb + 2]; if (m + 2 == n) e2 = 3.4e38f;
        float e3 = (sqn - 2.f * d3) + sqt[mb + 3]; if (m + 3 == n) e3 = 3.4e38f;
        INSERT(e0, m + 0);
        INSERT(e1, m + 1);
        INSERT(e2, m + 2);
        INSERT(e3, m + 3);
    }
    size_t base = (((size_t)(b * 4096 + n)) * 32 + ch) * 16;
    #pragma unroll
    for (int s = 0; s < 16; ++s) { pd[base + s] = bd[s]; pi[base + s] = bi[s]; }
}

// ---------------- KNN phase 2: wave-per-query extract-min x16 ----------------
// 512 partial entries per query; neighbor SET is all that matters (k feeds max).
__global__ __launch_bounds__(256) void knn_merge_kernel(const float* __restrict__ pd,
                                                        const int* __restrict__ pi,
                                                        int* __restrict__ idxw) {
    int tid = threadIdx.x;
    int lane = tid & 63;
    int q = blockIdx.x * 4 + (tid >> 6);               // 2048 blocks, 4 queries each
    size_t base = (size_t)q * 512;

    float d[8]; int ix[8];
    #pragma unroll
    for (int j = 0; j < 8; ++j) {
        d[j] = pd[base + lane + 64 * j];
        ix[j] = pi[base + lane + 64 * j];
    }

    for (int e = 0; e < 16; ++e) {
        float lmd = d[0]; int lmi = ix[0];
        #pragma unroll
        for (int j = 1; j < 8; ++j) {
            bool c = d[j] < lmd;
            lmd = c ? d[j] : lmd;
            lmi = c ? ix[j] : lmi;
        }
        float wm = lmd;
        #pragma unroll
        for (int off = 32; off; off >>= 1)
            wm = fminf(wm, __shfl_xor(wm, off));
        unsigned long long msk = __ballot(lmd == wm);
        int L = (int)__ffsll(msk) - 1;
        int wmi = __shfl(lmi, L);
        if (lane == 0) idxw[q * 16 + e] = wmi;
        if (lane == L) {
            #pragma unroll
            for (int j = 0; j < 8; ++j)
                if (ix[j] == wmi) d[j] = 3.4e38f;
        }
    }
}

// ---------------- weight prep: bf16 W2/W3, split+transpose W1 ----------------
__global__ __launch_bounds__(256) void prep_kernel(const float* __restrict__ W1,
                                                   const float* __restrict__ W2,
                                                   const float* __restrict__ W3,
                                                   u16* __restrict__ W2bf,
                                                   u16* __restrict__ W3bf,
                                                   float* __restrict__ W1dT,
                                                   float* __restrict__ W1bT) {
    int t = blockIdx.x * 256 + threadIdx.x;            // 65536
    W2bf[t] = f2bf(W2[t]);
    if (t < 16384) {
        W3bf[t] = f2bf(W3[t]);
        int c = t >> 8, h = t & 255;
        float wa = W1[h * 128 + c];
        float wb = W1[h * 128 + 64 + c];
        W1dT[t] = wa - wb;                             // [c][h]
        W1bT[t] = wb;                                  // [c][h]
    }
}

// ---------------- Qn[b][m][h] = W1b @ mean_pc ----------------
__global__ __launch_bounds__(256) void q_kernel(const float* __restrict__ pc,
                                                const float* __restrict__ W1bT,
                                                float* __restrict__ Qn) {
    int h = threadIdx.x;
    int bid = blockIdx.x;                              // 2048
    int b = bid >> 10, m0 = (bid & 1023) * 4;
    float a0 = 0.f, a1 = 0.f, a2 = 0.f, a3 = 0.f;
    for (int c = 0; c < 64; ++c) {
        float w = W1bT[c * 256 + h];
        const float* pr = pc + ((size_t)(b * 64 + c)) * 4096 + m0;
        a0 = fmaf(w, pr[0], a0);
        a1 = fmaf(w, pr[1], a1);
        a2 = fmaf(w, pr[2], a2);
        a3 = fmaf(w, pr[3], a3);
    }
    size_t ob = ((size_t)(b * 4096 + m0)) * 256 + h;
    Qn[ob] = a0; Qn[ob + 256] = a1; Qn[ob + 512] = a2; Qn[ob + 768] = a3;
}

// ---------------- P[b][d][n][h] = (W1a-W1b) @ x + b1 ----------------
__global__ __launch_bounds__(256) void p_kernel(const float* __restrict__ x,
                                                const float* __restrict__ W1dT,
                                                const float* __restrict__ b1,
                                                float* __restrict__ P) {
    int h = threadIdx.x;
    int bid = blockIdx.x;                              // 6144
    int b = bid / 3072;
    int rem = bid % 3072;
    int d = rem >> 10;
    int n0 = (rem & 1023) * 4;
    float bias = b1[h];
    float a0 = bias, a1 = bias, a2 = bias, a3 = bias;
    for (int c = 0; c < 64; ++c) {
        float w = W1dT[c * 256 + h];
        const float* xr = x + ((size_t)((b * 64 + c) * 3 + d)) * 4096 + n0;
        a0 = fmaf(w, xr[0], a0);
        a1 = fmaf(w, xr[1], a1);
        a2 = fmaf(w, xr[2], a2);
        a3 = fmaf(w, xr[3], a3);
    }
    size_t ob = ((size_t)((b * 3 + d) * 4096 + n0)) * 256 + h;
    P[ob] = a0; P[ob + 256] = a1; P[ob + 512] = a2; P[ob + 768] = a3;
}

// ---------------- fused layer2+layer3+maxK+residual (bf16 MFMA) ----------------
// one block = 2 points (G=2): 96 columns (g,d,k), 256 threads = 4 waves
__global__ __launch_bounds__(256) void fused_mlp_kernel(const float* __restrict__ x,
                                                        const float* __restrict__ P,
                                                        const float* __restrict__ Qn,
                                                        const int* __restrict__ idxw,
                                                        const u16* __restrict__ W2bf,
                                                        const u16* __restrict__ W3bf,
                                                        const float* __restrict__ b2,
                                                        const float* __restrict__ b3,
                                                        float* __restrict__ out) {
    __shared__ u16 hL[96][264];                        // stride 264: 16B-aligned rows, 2-way banks
    __shared__ float b2s[256];
    __shared__ float b3s[64];
    __shared__ int idxs[32];

    int tid = threadIdx.x;
    int bid = blockIdx.x;                              // 4096
    int b = bid >> 11;
    int n0 = (bid & 2047) * 2;

    b2s[tid] = b2[tid];
    if (tid < 64) b3s[tid] = b3[tid];
    if (tid < 32) {
        int g = tid >> 4, k = tid & 15;
        idxs[tid] = idxw[((size_t)(b * 4096 + n0 + g)) * 16 + k];
    }
    __syncthreads();

    // ---- build h1 = relu(P + Q) into LDS (bf16) ----
    int tsub = tid & 63, jgrp = tid >> 6;
    for (int it = 0; it < 24; ++it) {
        int j = it * 4 + jgrp;                         // 0..95
        int g = j / 48, jj = j % 48;
        int d = jj >> 4, k = jj & 15;
        int m = idxs[g * 16 + k];
        const float4* Pp = (const float4*)(P + ((size_t)((b * 3 + d) * 4096 + (n0 + g))) * 256) + tsub;
        const float4* Qp = (const float4*)(Qn + ((size_t)(b * 4096 + m)) * 256) + tsub;
        float4 pv = *Pp;
        float4 qv = *Qp;
        u16x4 hv;
        hv[0] = f2bf(fmaxf(pv.x + qv.x, 0.f));
        hv[1] = f2bf(fmaxf(pv.y + qv.y, 0.f));
        hv[2] = f2bf(fmaxf(pv.z + qv.z, 0.f));
        hv[3] = f2bf(fmaxf(pv.w + qv.w, 0.f));
        *(u16x4*)&hL[j][tsub * 4] = hv;
    }
    __syncthreads();

    int w = tid >> 6, lane = tid & 63;
    int cl = lane & 15, q = lane >> 4;

    // ---- layer 2: h2 = relu(W2 @ h1 + b2), 256 rows x 96 cols ----
    f32x4 acc[4][6];
    #pragma unroll
    for (int i = 0; i < 4; ++i)
        #pragma unroll
        for (int jt = 0; jt < 6; ++jt)
            acc[i][jt] = (f32x4){0.f, 0.f, 0.f, 0.f};

    const u16* Arow = W2bf + ((size_t)(w * 64 + cl)) * 256 + q * 8;
    for (int kt = 0; kt < 8; ++kt) {
        int k0 = kt * 32;
        bf16x8 a[4], bb[6];
        #pragma unroll
        for (int i = 0; i < 4; ++i)
            a[i] = *(const bf16x8*)(Arow + i * 16 * 256 + k0);
        #pragma unroll
        for (int jt = 0; jt < 6; ++jt)
            bb[jt] = *(const bf16x8*)(&hL[jt * 16 + cl][k0 + q * 8]);
        #pragma unroll
        for (int i = 0; i < 4; ++i)
            #pragma unroll
            for (int jt = 0; jt < 6; ++jt)
                acc[i][jt] = __builtin_amdgcn_mfma_f32_16x16x32_bf16(a[i], bb[jt], acc[i][jt], 0, 0, 0);
    }
    __syncthreads();   // everyone done reading h1

    // write h2 (bf16) into the same LDS buffer
    #pragma unroll
    for (int i = 0; i < 4; ++i) {
        int rowb = w * 64 + i * 16 + q * 4;
        #pragma unroll
        for (int jt = 0; jt < 6; ++jt) {
            f32x4 v = acc[i][jt];
            u16x4 hv;
            hv[0] = f2bf(fmaxf(v[0] + b2s[rowb + 0], 0.f));
            hv[1] = f2bf(fmaxf(v[1] + b2s[rowb + 1], 0.f));
            hv[2] = f2bf(fmaxf(v[2] + b2s[rowb + 2], 0.f));
            hv[3] = f2bf(fmaxf(v[3] + b2s[rowb + 3], 0.f));
            *(u16x4*)&hL[jt * 16 + cl][rowb] = hv;
        }
    }
    __syncthreads();

    // ---- layer 3: r = W3 @ h2 + b3, 64 rows x 96 cols; wave w -> rows w*16..w*16+15 ----
    f32x4 acc3[6];
    #pragma unroll
    for (int jt = 0; jt < 6; ++jt) acc3[jt] = (f32x4){0.f, 0.f, 0.f, 0.f};

    const u16* A3row = W3bf + ((size_t)(w * 16 + cl)) * 256 + q * 8;
    for (int kt = 0; kt < 8; ++kt) {
        int k0 = kt * 32;
        bf16x8 a3 = *(const bf16x8*)(A3row + k0);
        #pragma unroll
        for (int jt = 0; jt < 6; ++jt) {
            bf16x8 bb = *(const bf16x8*)(&hL[jt * 16 + cl][k0 + q * 8]);
            acc3[jt] = __builtin_amdgcn_mfma_f32_16x16x32_bf16(a3, bb, acc3[jt], 0, 0, 0);
        }
    }

    // ---- epilogue: +b3, max over k (16 cols of each tile), +x, store ----
    #pragma unroll
    for (int jt = 0; jt < 6; ++jt) {
        int g = jt / 3, d = jt % 3;
        int n = n0 + g;
        int rowb = w * 16 + q * 4;
        f32x4 v = acc3[jt];
        v[0] += b3s[rowb + 0];
        v[1] += b3s[rowb + 1];
        v[2] += b3s[rowb + 2];
        v[3] += b3s[rowb + 3];
        #pragma unroll
        for (int off = 1; off < 16; off <<= 1) {
            v[0] = fmaxf(v[0], __shfl_xor(v[0], off));
            v[1] = fmaxf(v[1], __shfl_xor(v[1], off));
            v[2] = fmaxf(v[2], __shfl_xor(v[2], off));
            v[3] = fmaxf(v[3], __shfl_xor(v[3], off));
        }
        if (cl == 0) {
            #pragma unroll
            for (int r = 0; r < 4; ++r) {
                size_t addr = ((size_t)((b * 64 + rowb + r) * 3 + d)) * 4096 + n;
                out[addr] = v[r] + x[addr];
            }
        }
    }
}

extern "C" void kernel_launch(void* const* d_in, const int* in_sizes, int n_in,
                              void* d_out, int out_size, void* d_ws, size_t ws_size,
                              hipStream_t stream) {
    (void)in_sizes; (void)n_in; (void)out_size; (void)ws_size;
    const float* x  = (const float*)d_in[0];
    const float* W1 = (const float*)d_in[1];
    const float* b1 = (const float*)d_in[2];
    const float* W2 = (const float*)d_in[3];
    const float* b2 = (const float*)d_in[4];
    const float* W3 = (const float*)d_in[5];
    const float* b3 = (const float*)d_in[6];
    float* out = (float*)d_out;

    char* ws = (char*)d_ws;
    float* pc   = (float*)(ws + 0);          // 2,097,152 B  (B,C,N)
    float* sq   = (float*)(ws + 2097152);    //    32,768 B  (B,N)
    int*   idxw = (int*)  (ws + 2129920);    //   524,288 B  (B,N,K)
    float* Qn   = (float*)(ws + 2654208);    // 8,388,608 B  (B,N,H)
    float* P    = (float*)(ws + 11042816);   // 25,165,824 B (B,D,N,H)
    u16*   W2bf = (u16*)  (ws + 36208640);   //   131,072 B
    u16*   W3bf = (u16*)  (ws + 36339712);   //    32,768 B
    float* W1dT = (float*)(ws + 36372480);   //    65,536 B
    float* W1bT = (float*)(ws + 36438016);   //    65,536 B
    // KNN partials (8192 q x 512 entries x 4 B = 16,777,216 B each) alias the
    // not-yet-written Qn+P regions; q_kernel/p_kernel run after knn_merge.
    float* pd   = (float*)(ws + 2654208);    // 16,777,216 B (ends 19,431,424)
    int*   pi   = (int*)  (ws + 19431424);   // 16,777,216 B (ends 36,208,640)

    mean_kernel<<<2048, 256, 0, stream>>>(x, pc);
    sq_kernel<<<32, 256, 0, stream>>>(pc, sq);
    knn_part_kernel<<<1024, 256, 0, stream>>>(pc, sq, pd, pi);
    knn_merge_kernel<<<2048, 256, 0, stream>>>(pd, pi, idxw);
    prep_kernel<<<256, 256, 0, stream>>>(W1, W2, W3, W2bf, W3bf, W1dT, W1bT);
    q_kernel<<<2048, 256, 0, stream>>>(pc, W1bT, Qn);
    p_kernel<<<6144, 256, 0, stream>>>(x, W1dT, b1, P);
    fused_mlp_kernel<<<4096, 256, 0, stream>>>(x, P, Qn, idxw, W2bf, W3bf, b2, b3, out);
}